// Round 12
// baseline (714.305 us; speedup 1.0000x reference)
//
#include <hip/hip_runtime.h>
#include <hip/hip_bf16.h>

#define F 64
#define GRAPHS 512
#define CLASSES 10
#define SCAN_T 1024
#define NBLK 256       // histogram/scatter blocks (power of 2)
#define OUTCAP 8448    // bucket CSR slots (mean ~4350, sigma ~64 — never overflows)

// ---------------- phase 1: per-block LDS histogram (+gbounds, +W1 transpose) ----------------
__global__ void hist_gb_kernel(const int* __restrict__ ei, int E, int NB,
                               int* __restrict__ hist,
                               const int* __restrict__ batch, int N, int* __restrict__ gstart,
                               const float* __restrict__ W1, float* __restrict__ Wt) {
    int blk = blockIdx.x, tid = threadIdx.x;
    if (blk < NBLK) {
        __shared__ int lh[512];
        lh[tid] = 0; lh[tid + 256] = 0;
        __syncthreads();
        int chunk = (E + NBLK - 1) / NBLK;
        int b = blk * chunk, e = min(E, b + chunk);
        for (int i = b + tid; i < e; i += 256) atomicAdd(&lh[ei[E + i] >> 8], 1);
        __syncthreads();
        for (int j = tid; j < NB; j += 256) hist[j * NBLK + blk] = lh[j];
    } else if (blk < NBLK + 3) {
        int g = (blk - NBLK) * 256 + tid;
        if (g > GRAPHS) return;
        int lo = 0, hi = N;
        while (lo < hi) {
            int mid = (lo + hi) >> 1;
            if (batch[mid] < g) lo = mid + 1; else hi = mid;
        }
        gstart[g] = lo;
    } else {
        // W1 transpose: Wt[c][k] = W1[k][c]  (64 x 128)
        int c = tid & 63;
        int k0 = (tid >> 6) * 32;
        for (int k = k0; k < k0 + 32; ++k) Wt[c * 128 + k] = W1[k * 64 + c];
    }
}

// ---------------- phase 2: exclusive scan of hist (contiguous layout) ----------------
__global__ void hscan_partial(const int* __restrict__ hist, int M,
                              int* __restrict__ partial) {
    int t = blockIdx.x * blockDim.x + threadIdx.x;
    int chunk = (M + SCAN_T - 1) / SCAN_T;
    int b = t * chunk, e = min(M, b + chunk);
    int s = 0;
    for (int l = b; l < e; ++l) s += hist[l];
    partial[t] = s;
}

__global__ void scan_block(int* __restrict__ partial) {   // 1 block, 1024 threads
    __shared__ int wsum[16];
    int t = threadIdx.x;
    int lane = t & 63, w = t >> 6;
    int orig = partial[t];
    int v = orig;
    #pragma unroll
    for (int o = 1; o < 64; o <<= 1) {
        int u = __shfl_up(v, o);
        if (lane >= o) v += u;
    }
    if (lane == 63) wsum[w] = v;
    __syncthreads();
    if (t == 0) {
        int run = 0;
        for (int i = 0; i < 16; ++i) { int x = wsum[i]; wsum[i] = run; run += x; }
    }
    __syncthreads();
    v += wsum[w];
    partial[t] = v - orig;   // exclusive prefix
}

__global__ void hscan_final(const int* __restrict__ hist, const int* __restrict__ partial,
                            int M, int* __restrict__ shist) {
    int t = blockIdx.x * blockDim.x + threadIdx.x;
    int chunk = (M + SCAN_T - 1) / SCAN_T;
    int b = t * chunk, e = min(M, b + chunk);
    int run = partial[t];
    for (int l = b; l < e; ++l) {
        int v = hist[l];
        shist[l] = run;
        run += v;
    }
}

// ---------------- phase 3: binned scatter, LDS cursors only ----------------
__global__ void scatter3(const int* __restrict__ ei, int E, int NB,
                         const int* __restrict__ shist, unsigned* __restrict__ stage) {
    __shared__ int offs[512];
    int blk = blockIdx.x, tid = threadIdx.x;
    for (int j = tid; j < NB; j += 256) offs[j] = shist[j * NBLK + blk];
    __syncthreads();
    int chunk = (E + NBLK - 1) / NBLK;
    int b = blk * chunk, e = min(E, b + chunk);
    for (int i = b + tid; i < e; i += 256) {
        int s = ei[i], d = ei[E + i];
        int pos = atomicAdd(&offs[d >> 8], 1);
        stage[pos] = (unsigned)s | ((unsigned)(d & 255) << 24);
    }
}

// ---------------- phase 4: per-bucket place; derives rowptr; coalesced CSR flush ---------
__global__ void place2(const unsigned* __restrict__ stage, const int* __restrict__ shist,
                       int* __restrict__ rowptr, int* __restrict__ csr_src,
                       int N, int E, int NB) {
    __shared__ int cnt[256];
    __shared__ int cur[256];
    __shared__ int wsum[4];
    __shared__ int out[OUTCAP];
    int tid = threadIdx.x, bkt = blockIdx.x;
    int n0 = bkt << 8;
    int nn = min(256, N - n0);
    int eb = shist[bkt * NBLK];
    int ee = (bkt == NB - 1) ? E : shist[(bkt + 1) * NBLK];
    int elen = ee - eb;
    int cb = eb + n0;
    int csrlen = elen + nn;
    cnt[tid] = 0;
    __syncthreads();
    for (int i = tid; i < elen; i += 256) atomicAdd(&cnt[stage[eb + i] >> 24], 1);
    __syncthreads();
    int v = (tid < nn) ? cnt[tid] + 1 : 0;
    int lane = tid & 63, w = tid >> 6;
    int incl = v;
    #pragma unroll
    for (int o = 1; o < 64; o <<= 1) {
        int u = __shfl_up(incl, o);
        if (lane >= o) incl += u;
    }
    if (lane == 63) wsum[w] = incl;
    __syncthreads();
    if (tid == 0) {
        int run = 0;
        for (int i = 0; i < 4; ++i) { int t = wsum[i]; wsum[i] = run; run += t; }
    }
    __syncthreads();
    int excl = incl - v + wsum[w];
    cur[tid] = excl;
    if (tid < nn) rowptr[n0 + tid] = cb + excl;
    if (bkt == NB - 1 && tid == 0) rowptr[N] = E + N;
    __syncthreads();
    if (csrlen <= OUTCAP) {
        for (int i = tid; i < elen; i += 256) {
            unsigned wd = stage[eb + i];
            int p = atomicAdd(&cur[wd >> 24], 1);
            out[p] = (int)(wd & 0xFFFFFFu);
        }
        __syncthreads();
        if (tid < nn) out[cur[tid]] = n0 + tid;
        __syncthreads();
        for (int i = tid; i < csrlen; i += 256) csr_src[cb + i] = out[i];
    } else {
        for (int i = tid; i < elen; i += 256) {
            unsigned wd = stage[eb + i];
            int p = atomicAdd(&cur[wd >> 24], 1);
            csr_src[cb + p] = (int)(wd & 0xFFFFFFu);
        }
        __syncthreads();
        if (tid < nn) csr_src[cb + cur[tid]] = n0 + tid;
    }
}

// ---------------- layer-1 GEMM (K=128): W streamed from global (transposed, L1-resident) ---
// LDS only stages x rows + packed output (10 KB -> ~8 blocks/CU vs 3 with the W-tile in LDS).
__global__ void gemm_kernel(const float* __restrict__ x, const float* __restrict__ Wt,
                            const float* __restrict__ asrc, const float* __restrict__ adst,
                            unsigned* __restrict__ hb, float* __restrict__ es,
                            float* __restrict__ ed, int N) {
    constexpr int ROWS = 16;
    constexpr int K = 128;
    constexpr int K4 = K / 4;
    __shared__ float xs[ROWS * K];
    __shared__ unsigned hs[ROWS * 32];
    int base = blockIdx.x * ROWS;
    int nrows = min(ROWS, N - base);
    float4* xs4 = (float4*)xs;
    const float4* x4 = (const float4*)x;
    for (int i = threadIdx.x; i < nrows * K4; i += 256) {
        int r = i / K4, k4 = i - r * K4;
        xs4[r * K4 + k4] = x4[(size_t)(base + r) * K4 + k4];
    }
    __syncthreads();

    int wave = threadIdx.x >> 6, lane = threadIdx.x & 63;
    float as_l = asrc[lane];
    float ad_l = adst[lane];
    const float4* wr = (const float4*)&Wt[(size_t)lane * K];   // global, L1/L2-resident
    const float4* xr0 = (const float4*)&xs[(wave + 0) * K];
    const float4* xr1 = (const float4*)&xs[(wave + 4) * K];
    const float4* xr2 = (const float4*)&xs[(wave + 8) * K];
    const float4* xr3 = (const float4*)&xs[(wave + 12) * K];
    float a0 = 0.f, a1 = 0.f, a2 = 0.f, a3 = 0.f;
    #pragma unroll 8
    for (int k4 = 0; k4 < K4; ++k4) {
        float4 wv = wr[k4];
        float4 v0 = xr0[k4], v1 = xr1[k4], v2 = xr2[k4], v3 = xr3[k4];
        a0 = fmaf(v0.x, wv.x, fmaf(v0.y, wv.y, fmaf(v0.z, wv.z, fmaf(v0.w, wv.w, a0))));
        a1 = fmaf(v1.x, wv.x, fmaf(v1.y, wv.y, fmaf(v1.z, wv.z, fmaf(v1.w, wv.w, a1))));
        a2 = fmaf(v2.x, wv.x, fmaf(v2.y, wv.y, fmaf(v2.z, wv.z, fmaf(v2.w, wv.w, a2))));
        a3 = fmaf(v3.x, wv.x, fmaf(v3.y, wv.y, fmaf(v3.z, wv.z, fmaf(v3.w, wv.w, a3))));
    }
    float accs[4] = {a0, a1, a2, a3};
    #pragma unroll
    for (int rr = 0; rr < 4; ++rr) {
        int r = wave + 4 * rr;
        float acc = accs[rr];
        unsigned ub = __float_as_uint(acc);
        unsigned rb = (ub + 0x7FFF + ((ub >> 16) & 1)) >> 16;   // RNE bf16 bits
        unsigned pb = (unsigned)__shfl_xor((int)rb, 1);
        if ((lane & 1) == 0) hs[r * 32 + (lane >> 1)] = (pb << 16) | rb;
        float vs = acc * as_l;
        float vd = acc * ad_l;
        #pragma unroll
        for (int o = 32; o > 0; o >>= 1) {
            vs += __shfl_down(vs, o);
            vd += __shfl_down(vd, o);
        }
        if (lane == 0 && r < nrows) { es[base + r] = vs; ed[base + r] = vd; }
    }
    __syncthreads();
    unsigned* hbase = hb + (size_t)base * 32;
    for (int i = threadIdx.x; i < nrows * 32; i += 256) hbase[i] = hs[i];
}

// ---------------- aggregate: 2 nodes per wave; optional fused next-layer GEMM epilogue ----
template<bool FUSE>
__global__ void gat_agg_fused(const unsigned* __restrict__ hb_in, const float* __restrict__ es_in,
                              const float* __restrict__ ed_in, const int* __restrict__ rowptr,
                              const int* __restrict__ csr_src, const float* __restrict__ bias,
                              const float* __restrict__ Wn, const float* __restrict__ ans,
                              const float* __restrict__ and_,
                              float* __restrict__ xout, unsigned* __restrict__ hb_out,
                              float* __restrict__ es_out, float* __restrict__ ed_out, int N) {
    extern __shared__ float smem[];
    constexpr int KP = 68;
    float* Ws = smem;                                        // [64][68] (FUSE only)
    float2* sw = (float2*)(smem + (FUSE ? 64 * KP : 0));     // [8][64] (src,w) pairs
    float* xs = (float*)((char*)sw + 8 * 64 * 8);            // [8][64] output rows
    unsigned* hpack = (unsigned*)((char*)xs + 8 * 64 * 4);   // [8][32] (FUSE only)

    int wave = threadIdx.x >> 6, lane = threadIdx.x & 63;
    int hw = lane >> 5, sub = lane & 31;
    int base8 = blockIdx.x * 8;
    int nl = 2 * wave + hw;                // node-local 0..7
    int node = base8 + nl;

    if (FUSE) {
        int c = threadIdx.x & 63;
        int q0 = threadIdx.x >> 6;
        #pragma unroll
        for (int it = 0; it < 4; ++it) {
            int q = q0 + 4 * it;
            float4 v;
            v.x = Wn[(4 * q + 0) * F + c];
            v.y = Wn[(4 * q + 1) * F + c];
            v.z = Wn[(4 * q + 2) * F + c];
            v.w = Wn[(4 * q + 3) * F + c];
            *(float4*)&Ws[c * KP + 4 * q] = v;
        }
    }

    if (node < N) {
        int beg = rowptr[node], end = rowptr[node + 1];
        int cnt = end - beg;
        float edn = ed_in[node];
        float accL, accH, den;
        if (cnt <= 64) {
            int s1 = 0, s2 = 0;
            float e1 = -1e30f, e2 = -1e30f;
            if (sub < cnt) {
                s1 = csr_src[beg + sub];
                float t = es_in[s1] + edn;
                e1 = t > 0.f ? t : 0.2f * t;
            }
            if (sub + 32 < cnt) {
                s2 = csr_src[beg + 32 + sub];
                float t = es_in[s2] + edn;
                e2 = t > 0.f ? t : 0.2f * t;
            }
            float m = fmaxf(e1, e2);
            #pragma unroll
            for (int o = 16; o > 0; o >>= 1) m = fmaxf(m, __shfl_xor(m, o));
            float w1 = (sub < cnt) ? __expf(e1 - m) : 0.f;
            float w2 = (sub + 32 < cnt) ? __expf(e2 - m) : 0.f;
            den = w1 + w2;
            #pragma unroll
            for (int o = 16; o > 0; o >>= 1) den += __shfl_xor(den, o);
            sw[nl * 64 + sub] = make_float2(__int_as_float(s1), w1);
            sw[nl * 64 + 32 + sub] = make_float2(__int_as_float(s2), w2);
            float l0 = 0.f, l1 = 0.f, l2 = 0.f, l3 = 0.f;
            float h0 = 0.f, h1 = 0.f, h2 = 0.f, h3 = 0.f;
            int i = 0;
            for (; i + 3 < cnt; i += 4) {
                float2 p0 = sw[nl * 64 + i];
                float2 p1 = sw[nl * 64 + i + 1];
                float2 p2 = sw[nl * 64 + i + 2];
                float2 p3 = sw[nl * 64 + i + 3];
                unsigned q0 = hb_in[(size_t)__float_as_int(p0.x) * 32 + sub];
                unsigned q1 = hb_in[(size_t)__float_as_int(p1.x) * 32 + sub];
                unsigned q2 = hb_in[(size_t)__float_as_int(p2.x) * 32 + sub];
                unsigned q3 = hb_in[(size_t)__float_as_int(p3.x) * 32 + sub];
                l0 = fmaf(p0.y, __uint_as_float(q0 << 16), l0);
                h0 = fmaf(p0.y, __uint_as_float(q0 & 0xFFFF0000u), h0);
                l1 = fmaf(p1.y, __uint_as_float(q1 << 16), l1);
                h1 = fmaf(p1.y, __uint_as_float(q1 & 0xFFFF0000u), h1);
                l2 = fmaf(p2.y, __uint_as_float(q2 << 16), l2);
                h2 = fmaf(p2.y, __uint_as_float(q2 & 0xFFFF0000u), h2);
                l3 = fmaf(p3.y, __uint_as_float(q3 << 16), l3);
                h3 = fmaf(p3.y, __uint_as_float(q3 & 0xFFFF0000u), h3);
            }
            for (; i < cnt; ++i) {
                float2 pp = sw[nl * 64 + i];
                unsigned q = hb_in[(size_t)__float_as_int(pp.x) * 32 + sub];
                l0 = fmaf(pp.y, __uint_as_float(q << 16), l0);
                h0 = fmaf(pp.y, __uint_as_float(q & 0xFFFF0000u), h0);
            }
            accL = (l0 + l1) + (l2 + l3);
            accH = (h0 + h1) + (h2 + h3);
        } else {
            float m = -1e30f;
            for (int j = beg + sub; j < end; j += 32) {
                float e = es_in[csr_src[j]] + edn;
                e = e > 0.f ? e : 0.2f * e;
                m = fmaxf(m, e);
            }
            #pragma unroll
            for (int o = 16; o > 0; o >>= 1) m = fmaxf(m, __shfl_xor(m, o));
            accL = 0.f; accH = 0.f; den = 0.f;
            for (int j = beg; j < end; ++j) {
                int s = csr_src[j];
                float e = es_in[s] + edn;
                e = e > 0.f ? e : 0.2f * e;
                float w = __expf(e - m);
                den += w;
                unsigned q = hb_in[(size_t)s * 32 + sub];
                accL = fmaf(w, __uint_as_float(q << 16), accL);
                accH = fmaf(w, __uint_as_float(q & 0xFFFF0000u), accH);
            }
        }
        float inv = 1.0f / (den + 1e-16f);
        float2 b2v = ((const float2*)bias)[sub];
        float vL = accL * inv + b2v.x;
        float vH = accH * inv + b2v.y;
        vL = vL > 0.f ? vL : 0.f;
        vH = vH > 0.f ? vH : 0.f;
        ((float2*)&xs[nl * 64])[sub] = make_float2(vL, vH);
    }
    __syncthreads();

    int nrows = min(8, N - base8);
    {
        float* xbase = xout + (size_t)base8 * F;
        for (int i = threadIdx.x; i < nrows * 64; i += 256) xbase[i] = xs[i];
    }

    if (FUSE) {
        float as_l = ans[lane];
        float ad_l = and_[lane];
        // two rows per wave share the Ws column read (wv hoisted out of the row loop)
        int r0 = wave, r1 = wave + 4;
        const float4* xv0 = (const float4*)&xs[r0 * 64];
        const float4* xv1 = (const float4*)&xs[r1 * 64];
        const float4* wv4 = (const float4*)&Ws[lane * KP];
        float p0 = 0.f, p1 = 0.f, p2 = 0.f, p3 = 0.f;
        float q0 = 0.f, q1 = 0.f, q2 = 0.f, q3 = 0.f;
        #pragma unroll
        for (int k4 = 0; k4 < 16; ++k4) {
            float4 wv = wv4[k4];
            float4 a = xv0[k4], b = xv1[k4];
            p0 = fmaf(a.x, wv.x, p0);
            p1 = fmaf(a.y, wv.y, p1);
            p2 = fmaf(a.z, wv.z, p2);
            p3 = fmaf(a.w, wv.w, p3);
            q0 = fmaf(b.x, wv.x, q0);
            q1 = fmaf(b.y, wv.y, q1);
            q2 = fmaf(b.z, wv.z, q2);
            q3 = fmaf(b.w, wv.w, q3);
        }
        float haccs[2] = {(p0 + p1) + (p2 + p3), (q0 + q1) + (q2 + q3)};
        #pragma unroll
        for (int rr = 0; rr < 2; ++rr) {
            int r = wave + 4 * rr;
            int nd = base8 + r;
            if (nd < N) {
                float hacc = haccs[rr];
                float vs = hacc * as_l;
                float vd = hacc * ad_l;
                #pragma unroll
                for (int o = 32; o > 0; o >>= 1) {
                    vs += __shfl_down(vs, o);
                    vd += __shfl_down(vd, o);
                }
                if (lane == 0) { es_out[nd] = vs; ed_out[nd] = vd; }
                unsigned ub = __float_as_uint(hacc);
                unsigned rb = (ub + 0x7FFF + ((ub >> 16) & 1)) >> 16;
                unsigned pb = (unsigned)__shfl_xor((int)rb, 1);
                if ((lane & 1) == 0) hpack[r * 32 + (lane >> 1)] = (pb << 16) | rb;
            }
        }
        __syncthreads();
        unsigned* hbase = hb_out + (size_t)base8 * 32;
        for (int i = threadIdx.x; i < nrows * 32; i += 256) hbase[i] = hpack[i];
    }
}

// ---------------- mean pooling ----------------
__global__ void pool_kernel(const float* __restrict__ x1, const float* __restrict__ x2,
                            const float* __restrict__ x3, const int* __restrict__ gstart,
                            float* __restrict__ pooled) {
    int g = blockIdx.x >> 2;
    int seg = blockIdx.x & 3;
    int f = threadIdx.x;
    int lane = f & 63;
    const float* src = (f < 64) ? x1 : (f < 128) ? x2 : x3;
    int lo = gstart[g], hi = gstart[g + 1];
    int len = hi - lo;
    int chunk = (len + 3) >> 2;
    int b = lo + seg * chunk;
    int e = min(hi, b + chunk);
    float s0 = 0.f, s1 = 0.f, s2 = 0.f, s3 = 0.f;
    int i = b;
    for (; i + 3 < e; i += 4) {
        s0 += src[(size_t)i * F + lane];
        s1 += src[(size_t)(i + 1) * F + lane];
        s2 += src[(size_t)(i + 2) * F + lane];
        s3 += src[(size_t)(i + 3) * F + lane];
    }
    for (; i < e; ++i) s0 += src[(size_t)i * F + lane];
    float s = (s0 + s1) + (s2 + s3);
    atomicAdd(&pooled[g * 192 + f], s);
}

// ---------------- final linear + softmax ----------------
__global__ void head_kernel(const float* __restrict__ pooled, const int* __restrict__ gstart,
                            const float* __restrict__ Wo, const float* __restrict__ bo,
                            float* __restrict__ out) {
    int g = blockIdx.x * blockDim.x + threadIdx.x;
    if (g >= GRAPHS) return;
    int cntg = gstart[g + 1] - gstart[g];
    float inv = 1.0f / fmaxf((float)cntg, 1.0f);
    float acc[CLASSES];
    #pragma unroll
    for (int c = 0; c < CLASSES; ++c) acc[c] = bo[c];
    for (int f = 0; f < 192; ++f) {
        float p = pooled[g * 192 + f] * inv;
        #pragma unroll
        for (int c = 0; c < CLASSES; ++c) acc[c] = fmaf(p, Wo[f * CLASSES + c], acc[c]);
    }
    float mx = acc[0];
    #pragma unroll
    for (int c = 1; c < CLASSES; ++c) mx = fmaxf(mx, acc[c]);
    float s = 0.f;
    #pragma unroll
    for (int c = 0; c < CLASSES; ++c) { acc[c] = __expf(acc[c] - mx); s += acc[c]; }
    float invs = 1.0f / s;
    #pragma unroll
    for (int c = 0; c < CLASSES; ++c) out[g * CLASSES + c] = acc[c] * invs;
}

extern "C" void kernel_launch(void* const* d_in, const int* in_sizes, int n_in,
                              void* d_out, int out_size, void* d_ws, size_t ws_size,
                              hipStream_t stream) {
    const float* x   = (const float*)d_in[0];
    const int* ei    = (const int*)d_in[1];
    const int* batch = (const int*)d_in[2];
    const float* W1  = (const float*)d_in[3];
    const float* a1s = (const float*)d_in[4];
    const float* a1d = (const float*)d_in[5];
    const float* b1  = (const float*)d_in[6];
    const float* W2  = (const float*)d_in[7];
    const float* a2s = (const float*)d_in[8];
    const float* a2d = (const float*)d_in[9];
    const float* b2  = (const float*)d_in[10];
    const float* W3  = (const float*)d_in[11];
    const float* a3s = (const float*)d_in[12];
    const float* a3d = (const float*)d_in[13];
    const float* b3  = (const float*)d_in[14];
    const float* Wo  = (const float*)d_in[15];
    const float* bo  = (const float*)d_in[16];
    float* out = (float*)d_out;

    const int N = in_sizes[2];
    const int E = in_sizes[1] / 2;
    const int TOT = E + N;
    const int NB = (N + 255) >> 8;
    const int M  = NB * NBLK;

    char* p = (char*)d_ws;
    auto alloc = [&](size_t bytes) { char* r = p; p += (bytes + 255) & ~(size_t)255; return r; };
    float* x1      = (float*)alloc((size_t)N * F * 4);
    float* x2      = (float*)alloc((size_t)N * F * 4);
    float* x3      = (float*)alloc((size_t)N * F * 4);
    unsigned* hbA  = (unsigned*)alloc((size_t)N * 32 * 4);
    unsigned* hbB  = (unsigned*)alloc((size_t)N * 32 * 4);
    float* esA     = (float*)alloc((size_t)N * 4);
    float* edA     = (float*)alloc((size_t)N * 4);
    float* esB     = (float*)alloc((size_t)N * 4);
    float* edB     = (float*)alloc((size_t)N * 4);
    int* rowptr    = (int*)alloc((size_t)(N + 1) * 4);
    int* csr_src   = (int*)alloc((size_t)TOT * 4);
    unsigned* stage= (unsigned*)alloc((size_t)E * 4);
    int* hist      = (int*)alloc((size_t)M * 4);
    int* shist     = (int*)alloc((size_t)M * 4);
    int* partial   = (int*)alloc((size_t)SCAN_T * 4);
    float* pooled  = (float*)alloc((size_t)GRAPHS * 192 * 4);
    int* gstart    = (int*)alloc((size_t)(GRAPHS + 1) * 4);
    float* Wt      = (float*)alloc((size_t)128 * 64 * 4);    // W1 transposed

    hipMemsetAsync(pooled, 0, (size_t)GRAPHS * 192 * 4, stream);

    const int GB = (N + 15) / 16;
    const size_t SMF   = (size_t)(64 * 68) * 4 + 4096 + 2048 + 1024;   // Ws + sw + xs + hpack
    const size_t SMNF  = 4096 + 2048 + 1024;
    int agg_blocks = (N + 7) / 8;

    // CSR build (+ gbounds + W1 transpose riding along)
    hist_gb_kernel<<<NBLK + 4, 256, 0, stream>>>(ei, E, NB, hist, batch, N, gstart, W1, Wt);
    hscan_partial<<<SCAN_T / 256, 256, 0, stream>>>(hist, M, partial);
    scan_block<<<1, SCAN_T, 0, stream>>>(partial);
    hscan_final<<<SCAN_T / 256, 256, 0, stream>>>(hist, partial, M, shist);
    scatter3<<<NBLK, 256, 0, stream>>>(ei, E, NB, shist, stage);
    place2<<<NB, 256, 0, stream>>>(stage, shist, rowptr, csr_src, N, E, NB);

    // layer 1 GEMM (K=128), W streamed from global
    gemm_kernel<<<GB, 256, 0, stream>>>(x, Wt, a1s, a1d, hbA, esA, edA, N);
    // agg1 + fused gemm2
    gat_agg_fused<true><<<agg_blocks, 256, SMF, stream>>>(hbA, esA, edA, rowptr, csr_src, b1,
                                                          W2, a2s, a2d, x1, hbB, esB, edB, N);
    // agg2 + fused gemm3
    gat_agg_fused<true><<<agg_blocks, 256, SMF, stream>>>(hbB, esB, edB, rowptr, csr_src, b2,
                                                          W3, a3s, a3d, x2, hbA, esA, edA, N);
    // agg3 (no fusion)
    gat_agg_fused<false><<<agg_blocks, 256, SMNF, stream>>>(hbA, esA, edA, rowptr, csr_src, b3,
                                                            nullptr, nullptr, nullptr,
                                                            x3, nullptr, nullptr, nullptr, N);

    // readout
    pool_kernel<<<GRAPHS * 4, 192, 0, stream>>>(x1, x2, x3, gstart, pooled);
    head_kernel<<<(GRAPHS + 255) / 256, 256, 0, stream>>>(pooled, gstart, Wo, bo, out);
}

// Round 13
// 526.797 us; speedup vs baseline: 1.3559x; 1.3559x over previous
//
#include <hip/hip_runtime.h>
#include <hip/hip_bf16.h>

#define F 64
#define GRAPHS 512
#define CLASSES 10
#define SCAN_T 1024
#define NBLK 256       // histogram/scatter blocks (power of 2)
#define OUTCAP 8448    // bucket CSR slots (mean ~4350, sigma ~64 — never overflows)

// ---------------- phase 1: per-block LDS histogram (+gbounds, +W1 transpose) ----------------
__global__ void hist_gb_kernel(const int* __restrict__ ei, int E, int NB,
                               int* __restrict__ hist,
                               const int* __restrict__ batch, int N, int* __restrict__ gstart,
                               const float* __restrict__ W1, float* __restrict__ Wt) {
    int blk = blockIdx.x, tid = threadIdx.x;
    if (blk < NBLK) {
        __shared__ int lh[512];
        lh[tid] = 0; lh[tid + 256] = 0;
        __syncthreads();
        int chunk = (E + NBLK - 1) / NBLK;
        int b = blk * chunk, e = min(E, b + chunk);
        for (int i = b + tid; i < e; i += 256) atomicAdd(&lh[ei[E + i] >> 8], 1);
        __syncthreads();
        for (int j = tid; j < NB; j += 256) hist[j * NBLK + blk] = lh[j];
    } else if (blk < NBLK + 3) {
        int g = (blk - NBLK) * 256 + tid;
        if (g > GRAPHS) return;
        int lo = 0, hi = N;
        while (lo < hi) {
            int mid = (lo + hi) >> 1;
            if (batch[mid] < g) lo = mid + 1; else hi = mid;
        }
        gstart[g] = lo;
    } else {
        // W1 transpose: Wt[c][k] = W1[k][c]  (64 x 128)
        int c = tid & 63;
        int k0 = (tid >> 6) * 32;
        for (int k = k0; k < k0 + 32; ++k) Wt[c * 128 + k] = W1[k * 64 + c];
    }
}

// ---------------- phase 2: exclusive scan of hist (contiguous layout) ----------------
__global__ void hscan_partial(const int* __restrict__ hist, int M,
                              int* __restrict__ partial) {
    int t = blockIdx.x * blockDim.x + threadIdx.x;
    int chunk = (M + SCAN_T - 1) / SCAN_T;
    int b = t * chunk, e = min(M, b + chunk);
    int s = 0;
    for (int l = b; l < e; ++l) s += hist[l];
    partial[t] = s;
}

__global__ void scan_block(int* __restrict__ partial) {   // 1 block, 1024 threads
    __shared__ int wsum[16];
    int t = threadIdx.x;
    int lane = t & 63, w = t >> 6;
    int orig = partial[t];
    int v = orig;
    #pragma unroll
    for (int o = 1; o < 64; o <<= 1) {
        int u = __shfl_up(v, o);
        if (lane >= o) v += u;
    }
    if (lane == 63) wsum[w] = v;
    __syncthreads();
    if (t == 0) {
        int run = 0;
        for (int i = 0; i < 16; ++i) { int x = wsum[i]; wsum[i] = run; run += x; }
    }
    __syncthreads();
    v += wsum[w];
    partial[t] = v - orig;   // exclusive prefix
}

__global__ void hscan_final(const int* __restrict__ hist, const int* __restrict__ partial,
                            int M, int* __restrict__ shist) {
    int t = blockIdx.x * blockDim.x + threadIdx.x;
    int chunk = (M + SCAN_T - 1) / SCAN_T;
    int b = t * chunk, e = min(M, b + chunk);
    int run = partial[t];
    for (int l = b; l < e; ++l) {
        int v = hist[l];
        shist[l] = run;
        run += v;
    }
}

// ---------------- phase 3: binned scatter, LDS cursors only ----------------
__global__ void scatter3(const int* __restrict__ ei, int E, int NB,
                         const int* __restrict__ shist, unsigned* __restrict__ stage) {
    __shared__ int offs[512];
    int blk = blockIdx.x, tid = threadIdx.x;
    for (int j = tid; j < NB; j += 256) offs[j] = shist[j * NBLK + blk];
    __syncthreads();
    int chunk = (E + NBLK - 1) / NBLK;
    int b = blk * chunk, e = min(E, b + chunk);
    for (int i = b + tid; i < e; i += 256) {
        int s = ei[i], d = ei[E + i];
        int pos = atomicAdd(&offs[d >> 8], 1);
        stage[pos] = (unsigned)s | ((unsigned)(d & 255) << 24);
    }
}

// ---------------- phase 4: per-bucket place; derives rowptr; coalesced CSR flush ---------
__global__ void place2(const unsigned* __restrict__ stage, const int* __restrict__ shist,
                       int* __restrict__ rowptr, int* __restrict__ csr_src,
                       int N, int E, int NB) {
    __shared__ int cnt[256];
    __shared__ int cur[256];
    __shared__ int wsum[4];
    __shared__ int out[OUTCAP];
    int tid = threadIdx.x, bkt = blockIdx.x;
    int n0 = bkt << 8;
    int nn = min(256, N - n0);
    int eb = shist[bkt * NBLK];
    int ee = (bkt == NB - 1) ? E : shist[(bkt + 1) * NBLK];
    int elen = ee - eb;
    int cb = eb + n0;
    int csrlen = elen + nn;
    cnt[tid] = 0;
    __syncthreads();
    for (int i = tid; i < elen; i += 256) atomicAdd(&cnt[stage[eb + i] >> 24], 1);
    __syncthreads();
    int v = (tid < nn) ? cnt[tid] + 1 : 0;
    int lane = tid & 63, w = tid >> 6;
    int incl = v;
    #pragma unroll
    for (int o = 1; o < 64; o <<= 1) {
        int u = __shfl_up(incl, o);
        if (lane >= o) incl += u;
    }
    if (lane == 63) wsum[w] = incl;
    __syncthreads();
    if (tid == 0) {
        int run = 0;
        for (int i = 0; i < 4; ++i) { int t = wsum[i]; wsum[i] = run; run += t; }
    }
    __syncthreads();
    int excl = incl - v + wsum[w];
    cur[tid] = excl;
    if (tid < nn) rowptr[n0 + tid] = cb + excl;
    if (bkt == NB - 1 && tid == 0) rowptr[N] = E + N;
    __syncthreads();
    if (csrlen <= OUTCAP) {
        for (int i = tid; i < elen; i += 256) {
            unsigned wd = stage[eb + i];
            int p = atomicAdd(&cur[wd >> 24], 1);
            out[p] = (int)(wd & 0xFFFFFFu);
        }
        __syncthreads();
        if (tid < nn) out[cur[tid]] = n0 + tid;
        __syncthreads();
        for (int i = tid; i < csrlen; i += 256) csr_src[cb + i] = out[i];
    } else {
        for (int i = tid; i < elen; i += 256) {
            unsigned wd = stage[eb + i];
            int p = atomicAdd(&cur[wd >> 24], 1);
            csr_src[cb + p] = (int)(wd & 0xFFFFFFu);
        }
        __syncthreads();
        if (tid < nn) csr_src[cb + cur[tid]] = n0 + tid;
    }
}

// ---------------- layer-1 GEMM (K=128): W streamed from global (transposed, L1-resident) ---
__global__ void gemm_kernel(const float* __restrict__ x, const float* __restrict__ Wt,
                            const float* __restrict__ asrc, const float* __restrict__ adst,
                            unsigned* __restrict__ hb, float* __restrict__ es,
                            float* __restrict__ ed, int N) {
    constexpr int ROWS = 16;
    constexpr int K = 128;
    constexpr int K4 = K / 4;
    __shared__ float xs[ROWS * K];
    __shared__ unsigned hs[ROWS * 32];
    int base = blockIdx.x * ROWS;
    int nrows = min(ROWS, N - base);
    float4* xs4 = (float4*)xs;
    const float4* x4 = (const float4*)x;
    for (int i = threadIdx.x; i < nrows * K4; i += 256) {
        int r = i / K4, k4 = i - r * K4;
        xs4[r * K4 + k4] = x4[(size_t)(base + r) * K4 + k4];
    }
    __syncthreads();

    int wave = threadIdx.x >> 6, lane = threadIdx.x & 63;
    float as_l = asrc[lane];
    float ad_l = adst[lane];
    const float4* wr = (const float4*)&Wt[(size_t)lane * K];   // global, L1/L2-resident
    const float4* xr0 = (const float4*)&xs[(wave + 0) * K];
    const float4* xr1 = (const float4*)&xs[(wave + 4) * K];
    const float4* xr2 = (const float4*)&xs[(wave + 8) * K];
    const float4* xr3 = (const float4*)&xs[(wave + 12) * K];
    float a0 = 0.f, a1 = 0.f, a2 = 0.f, a3 = 0.f;
    #pragma unroll 8
    for (int k4 = 0; k4 < K4; ++k4) {
        float4 wv = wr[k4];
        float4 v0 = xr0[k4], v1 = xr1[k4], v2 = xr2[k4], v3 = xr3[k4];
        a0 = fmaf(v0.x, wv.x, fmaf(v0.y, wv.y, fmaf(v0.z, wv.z, fmaf(v0.w, wv.w, a0))));
        a1 = fmaf(v1.x, wv.x, fmaf(v1.y, wv.y, fmaf(v1.z, wv.z, fmaf(v1.w, wv.w, a1))));
        a2 = fmaf(v2.x, wv.x, fmaf(v2.y, wv.y, fmaf(v2.z, wv.z, fmaf(v2.w, wv.w, a2))));
        a3 = fmaf(v3.x, wv.x, fmaf(v3.y, wv.y, fmaf(v3.z, wv.z, fmaf(v3.w, wv.w, a3))));
    }
    float accs[4] = {a0, a1, a2, a3};
    #pragma unroll
    for (int rr = 0; rr < 4; ++rr) {
        int r = wave + 4 * rr;
        float acc = accs[rr];
        unsigned ub = __float_as_uint(acc);
        unsigned rb = (ub + 0x7FFF + ((ub >> 16) & 1)) >> 16;   // RNE bf16 bits
        unsigned pb = (unsigned)__shfl_xor((int)rb, 1);
        if ((lane & 1) == 0) hs[r * 32 + (lane >> 1)] = (pb << 16) | rb;
        float vs = acc * as_l;
        float vd = acc * ad_l;
        #pragma unroll
        for (int o = 32; o > 0; o >>= 1) {
            vs += __shfl_down(vs, o);
            vd += __shfl_down(vd, o);
        }
        if (lane == 0 && r < nrows) { es[base + r] = vs; ed[base + r] = vd; }
    }
    __syncthreads();
    unsigned* hbase = hb + (size_t)base * 32;
    for (int i = threadIdx.x; i < nrows * 32; i += 256) hbase[i] = hs[i];
}

// ---------------- aggregate: 2 nodes per wave; optional fused next-layer GEMM epilogue ----
// Epilogue kept as two independent per-row loops: the "hoisted" 8-accumulator variant
// raised register demand past the compiler's cap and spilled INSIDE the gather loop
// (R12: VGPR 28->64, +555MB HBM scratch traffic, agg 83->176us). Do not re-hoist.
template<bool FUSE>
__global__ void gat_agg_fused(const unsigned* __restrict__ hb_in, const float* __restrict__ es_in,
                              const float* __restrict__ ed_in, const int* __restrict__ rowptr,
                              const int* __restrict__ csr_src, const float* __restrict__ bias,
                              const float* __restrict__ Wn, const float* __restrict__ ans,
                              const float* __restrict__ and_,
                              float* __restrict__ xout, unsigned* __restrict__ hb_out,
                              float* __restrict__ es_out, float* __restrict__ ed_out, int N) {
    extern __shared__ float smem[];
    constexpr int KP = 68;
    float* Ws = smem;                                        // [64][68] (FUSE only)
    float2* sw = (float2*)(smem + (FUSE ? 64 * KP : 0));     // [8][64] (src,w) pairs
    float* xs = (float*)((char*)sw + 8 * 64 * 8);            // [8][64] output rows
    unsigned* hpack = (unsigned*)((char*)xs + 8 * 64 * 4);   // [8][32] (FUSE only)

    int wave = threadIdx.x >> 6, lane = threadIdx.x & 63;
    int hw = lane >> 5, sub = lane & 31;
    int base8 = blockIdx.x * 8;
    int nl = 2 * wave + hw;                // node-local 0..7
    int node = base8 + nl;

    if (FUSE) {
        int c = threadIdx.x & 63;
        int q0 = threadIdx.x >> 6;
        #pragma unroll
        for (int it = 0; it < 4; ++it) {
            int q = q0 + 4 * it;
            float4 v;
            v.x = Wn[(4 * q + 0) * F + c];
            v.y = Wn[(4 * q + 1) * F + c];
            v.z = Wn[(4 * q + 2) * F + c];
            v.w = Wn[(4 * q + 3) * F + c];
            *(float4*)&Ws[c * KP + 4 * q] = v;
        }
    }

    if (node < N) {
        int beg = rowptr[node], end = rowptr[node + 1];
        int cnt = end - beg;
        float edn = ed_in[node];
        float accL, accH, den;
        if (cnt <= 64) {
            int s1 = 0, s2 = 0;
            float e1 = -1e30f, e2 = -1e30f;
            if (sub < cnt) {
                s1 = csr_src[beg + sub];
                float t = es_in[s1] + edn;
                e1 = t > 0.f ? t : 0.2f * t;
            }
            if (sub + 32 < cnt) {
                s2 = csr_src[beg + 32 + sub];
                float t = es_in[s2] + edn;
                e2 = t > 0.f ? t : 0.2f * t;
            }
            float m = fmaxf(e1, e2);
            #pragma unroll
            for (int o = 16; o > 0; o >>= 1) m = fmaxf(m, __shfl_xor(m, o));
            float w1 = (sub < cnt) ? __expf(e1 - m) : 0.f;
            float w2 = (sub + 32 < cnt) ? __expf(e2 - m) : 0.f;
            den = w1 + w2;
            #pragma unroll
            for (int o = 16; o > 0; o >>= 1) den += __shfl_xor(den, o);
            sw[nl * 64 + sub] = make_float2(__int_as_float(s1), w1);
            sw[nl * 64 + 32 + sub] = make_float2(__int_as_float(s2), w2);
            float l0 = 0.f, l1 = 0.f, l2 = 0.f, l3 = 0.f;
            float h0 = 0.f, h1 = 0.f, h2 = 0.f, h3 = 0.f;
            int i = 0;
            for (; i + 3 < cnt; i += 4) {
                float2 p0 = sw[nl * 64 + i];
                float2 p1 = sw[nl * 64 + i + 1];
                float2 p2 = sw[nl * 64 + i + 2];
                float2 p3 = sw[nl * 64 + i + 3];
                unsigned q0 = hb_in[(size_t)__float_as_int(p0.x) * 32 + sub];
                unsigned q1 = hb_in[(size_t)__float_as_int(p1.x) * 32 + sub];
                unsigned q2 = hb_in[(size_t)__float_as_int(p2.x) * 32 + sub];
                unsigned q3 = hb_in[(size_t)__float_as_int(p3.x) * 32 + sub];
                l0 = fmaf(p0.y, __uint_as_float(q0 << 16), l0);
                h0 = fmaf(p0.y, __uint_as_float(q0 & 0xFFFF0000u), h0);
                l1 = fmaf(p1.y, __uint_as_float(q1 << 16), l1);
                h1 = fmaf(p1.y, __uint_as_float(q1 & 0xFFFF0000u), h1);
                l2 = fmaf(p2.y, __uint_as_float(q2 << 16), l2);
                h2 = fmaf(p2.y, __uint_as_float(q2 & 0xFFFF0000u), h2);
                l3 = fmaf(p3.y, __uint_as_float(q3 << 16), l3);
                h3 = fmaf(p3.y, __uint_as_float(q3 & 0xFFFF0000u), h3);
            }
            for (; i < cnt; ++i) {
                float2 pp = sw[nl * 64 + i];
                unsigned q = hb_in[(size_t)__float_as_int(pp.x) * 32 + sub];
                l0 = fmaf(pp.y, __uint_as_float(q << 16), l0);
                h0 = fmaf(pp.y, __uint_as_float(q & 0xFFFF0000u), h0);
            }
            accL = (l0 + l1) + (l2 + l3);
            accH = (h0 + h1) + (h2 + h3);
        } else {
            float m = -1e30f;
            for (int j = beg + sub; j < end; j += 32) {
                float e = es_in[csr_src[j]] + edn;
                e = e > 0.f ? e : 0.2f * e;
                m = fmaxf(m, e);
            }
            #pragma unroll
            for (int o = 16; o > 0; o >>= 1) m = fmaxf(m, __shfl_xor(m, o));
            accL = 0.f; accH = 0.f; den = 0.f;
            for (int j = beg; j < end; ++j) {
                int s = csr_src[j];
                float e = es_in[s] + edn;
                e = e > 0.f ? e : 0.2f * e;
                float w = __expf(e - m);
                den += w;
                unsigned q = hb_in[(size_t)s * 32 + sub];
                accL = fmaf(w, __uint_as_float(q << 16), accL);
                accH = fmaf(w, __uint_as_float(q & 0xFFFF0000u), accH);
            }
        }
        float inv = 1.0f / (den + 1e-16f);
        float2 b2v = ((const float2*)bias)[sub];
        float vL = accL * inv + b2v.x;
        float vH = accH * inv + b2v.y;
        vL = vL > 0.f ? vL : 0.f;
        vH = vH > 0.f ? vH : 0.f;
        ((float2*)&xs[nl * 64])[sub] = make_float2(vL, vH);
    }
    __syncthreads();

    int nrows = min(8, N - base8);
    {
        float* xbase = xout + (size_t)base8 * F;
        for (int i = threadIdx.x; i < nrows * 64; i += 256) xbase[i] = xs[i];
    }

    if (FUSE) {
        float as_l = ans[lane];
        float ad_l = and_[lane];
        #pragma unroll
        for (int rr = 0; rr < 2; ++rr) {
            int r = wave + 4 * rr;
            int nd = base8 + r;
            if (nd < N) {
                const float4* xv4 = (const float4*)&xs[r * 64];
                const float4* wv4 = (const float4*)&Ws[lane * KP];
                float a0 = 0.f, a1 = 0.f, a2 = 0.f, a3 = 0.f;
                #pragma unroll
                for (int k4 = 0; k4 < 16; ++k4) {
                    float4 xv = xv4[k4];
                    float4 wv = wv4[k4];
                    a0 = fmaf(xv.x, wv.x, a0);
                    a1 = fmaf(xv.y, wv.y, a1);
                    a2 = fmaf(xv.z, wv.z, a2);
                    a3 = fmaf(xv.w, wv.w, a3);
                }
                float hacc = (a0 + a1) + (a2 + a3);
                float vs = hacc * as_l;
                float vd = hacc * ad_l;
                #pragma unroll
                for (int o = 32; o > 0; o >>= 1) {
                    vs += __shfl_down(vs, o);
                    vd += __shfl_down(vd, o);
                }
                if (lane == 0) { es_out[nd] = vs; ed_out[nd] = vd; }
                unsigned ub = __float_as_uint(hacc);
                unsigned rb = (ub + 0x7FFF + ((ub >> 16) & 1)) >> 16;
                unsigned pb = (unsigned)__shfl_xor((int)rb, 1);
                if ((lane & 1) == 0) hpack[r * 32 + (lane >> 1)] = (pb << 16) | rb;
            }
        }
        __syncthreads();
        unsigned* hbase = hb_out + (size_t)base8 * 32;
        for (int i = threadIdx.x; i < nrows * 32; i += 256) hbase[i] = hpack[i];
    }
}

// ---------------- mean pooling ----------------
__global__ void pool_kernel(const float* __restrict__ x1, const float* __restrict__ x2,
                            const float* __restrict__ x3, const int* __restrict__ gstart,
                            float* __restrict__ pooled) {
    int g = blockIdx.x >> 2;
    int seg = blockIdx.x & 3;
    int f = threadIdx.x;
    int lane = f & 63;
    const float* src = (f < 64) ? x1 : (f < 128) ? x2 : x3;
    int lo = gstart[g], hi = gstart[g + 1];
    int len = hi - lo;
    int chunk = (len + 3) >> 2;
    int b = lo + seg * chunk;
    int e = min(hi, b + chunk);
    float s0 = 0.f, s1 = 0.f, s2 = 0.f, s3 = 0.f;
    int i = b;
    for (; i + 3 < e; i += 4) {
        s0 += src[(size_t)i * F + lane];
        s1 += src[(size_t)(i + 1) * F + lane];
        s2 += src[(size_t)(i + 2) * F + lane];
        s3 += src[(size_t)(i + 3) * F + lane];
    }
    for (; i < e; ++i) s0 += src[(size_t)i * F + lane];
    float s = (s0 + s1) + (s2 + s3);
    atomicAdd(&pooled[g * 192 + f], s);
}

// ---------------- final linear + softmax ----------------
__global__ void head_kernel(const float* __restrict__ pooled, const int* __restrict__ gstart,
                            const float* __restrict__ Wo, const float* __restrict__ bo,
                            float* __restrict__ out) {
    int g = blockIdx.x * blockDim.x + threadIdx.x;
    if (g >= GRAPHS) return;
    int cntg = gstart[g + 1] - gstart[g];
    float inv = 1.0f / fmaxf((float)cntg, 1.0f);
    float acc[CLASSES];
    #pragma unroll
    for (int c = 0; c < CLASSES; ++c) acc[c] = bo[c];
    for (int f = 0; f < 192; ++f) {
        float p = pooled[g * 192 + f] * inv;
        #pragma unroll
        for (int c = 0; c < CLASSES; ++c) acc[c] = fmaf(p, Wo[f * CLASSES + c], acc[c]);
    }
    float mx = acc[0];
    #pragma unroll
    for (int c = 1; c < CLASSES; ++c) mx = fmaxf(mx, acc[c]);
    float s = 0.f;
    #pragma unroll
    for (int c = 0; c < CLASSES; ++c) { acc[c] = __expf(acc[c] - mx); s += acc[c]; }
    float invs = 1.0f / s;
    #pragma unroll
    for (int c = 0; c < CLASSES; ++c) out[g * CLASSES + c] = acc[c] * invs;
}

extern "C" void kernel_launch(void* const* d_in, const int* in_sizes, int n_in,
                              void* d_out, int out_size, void* d_ws, size_t ws_size,
                              hipStream_t stream) {
    const float* x   = (const float*)d_in[0];
    const int* ei    = (const int*)d_in[1];
    const int* batch = (const int*)d_in[2];
    const float* W1  = (const float*)d_in[3];
    const float* a1s = (const float*)d_in[4];
    const float* a1d = (const float*)d_in[5];
    const float* b1  = (const float*)d_in[6];
    const float* W2  = (const float*)d_in[7];
    const float* a2s = (const float*)d_in[8];
    const float* a2d = (const float*)d_in[9];
    const float* b2  = (const float*)d_in[10];
    const float* W3  = (const float*)d_in[11];
    const float* a3s = (const float*)d_in[12];
    const float* a3d = (const float*)d_in[13];
    const float* b3  = (const float*)d_in[14];
    const float* Wo  = (const float*)d_in[15];
    const float* bo  = (const float*)d_in[16];
    float* out = (float*)d_out;

    const int N = in_sizes[2];
    const int E = in_sizes[1] / 2;
    const int TOT = E + N;
    const int NB = (N + 255) >> 8;
    const int M  = NB * NBLK;

    char* p = (char*)d_ws;
    auto alloc = [&](size_t bytes) { char* r = p; p += (bytes + 255) & ~(size_t)255; return r; };
    float* x1      = (float*)alloc((size_t)N * F * 4);
    float* x2      = (float*)alloc((size_t)N * F * 4);
    float* x3      = (float*)alloc((size_t)N * F * 4);
    unsigned* hbA  = (unsigned*)alloc((size_t)N * 32 * 4);
    unsigned* hbB  = (unsigned*)alloc((size_t)N * 32 * 4);
    float* esA     = (float*)alloc((size_t)N * 4);
    float* edA     = (float*)alloc((size_t)N * 4);
    float* esB     = (float*)alloc((size_t)N * 4);
    float* edB     = (float*)alloc((size_t)N * 4);
    int* rowptr    = (int*)alloc((size_t)(N + 1) * 4);
    int* csr_src   = (int*)alloc((size_t)TOT * 4);
    unsigned* stage= (unsigned*)alloc((size_t)E * 4);
    int* hist      = (int*)alloc((size_t)M * 4);
    int* shist     = (int*)alloc((size_t)M * 4);
    int* partial   = (int*)alloc((size_t)SCAN_T * 4);
    float* pooled  = (float*)alloc((size_t)GRAPHS * 192 * 4);
    int* gstart    = (int*)alloc((size_t)(GRAPHS + 1) * 4);
    float* Wt      = (float*)alloc((size_t)128 * 64 * 4);    // W1 transposed

    hipMemsetAsync(pooled, 0, (size_t)GRAPHS * 192 * 4, stream);

    const int GB = (N + 15) / 16;
    const size_t SMF   = (size_t)(64 * 68) * 4 + 4096 + 2048 + 1024;   // Ws + sw + xs + hpack
    const size_t SMNF  = 4096 + 2048 + 1024;
    int agg_blocks = (N + 7) / 8;

    // CSR build (+ gbounds + W1 transpose riding along)
    hist_gb_kernel<<<NBLK + 4, 256, 0, stream>>>(ei, E, NB, hist, batch, N, gstart, W1, Wt);
    hscan_partial<<<SCAN_T / 256, 256, 0, stream>>>(hist, M, partial);
    scan_block<<<1, SCAN_T, 0, stream>>>(partial);
    hscan_final<<<SCAN_T / 256, 256, 0, stream>>>(hist, partial, M, shist);
    scatter3<<<NBLK, 256, 0, stream>>>(ei, E, NB, shist, stage);
    place2<<<NB, 256, 0, stream>>>(stage, shist, rowptr, csr_src, N, E, NB);

    // layer 1 GEMM (K=128), W streamed from global
    gemm_kernel<<<GB, 256, 0, stream>>>(x, Wt, a1s, a1d, hbA, esA, edA, N);
    // agg1 + fused gemm2
    gat_agg_fused<true><<<agg_blocks, 256, SMF, stream>>>(hbA, esA, edA, rowptr, csr_src, b1,
                                                          W2, a2s, a2d, x1, hbB, esB, edB, N);
    // agg2 + fused gemm3
    gat_agg_fused<true><<<agg_blocks, 256, SMF, stream>>>(hbB, esB, edB, rowptr, csr_src, b2,
                                                          W3, a3s, a3d, x2, hbA, esA, edA, N);
    // agg3 (no fusion)
    gat_agg_fused<false><<<agg_blocks, 256, SMNF, stream>>>(hbA, esA, edA, rowptr, csr_src, b3,
                                                            nullptr, nullptr, nullptr,
                                                            x3, nullptr, nullptr, nullptr, N);

    // readout
    pool_kernel<<<GRAPHS * 4, 192, 0, stream>>>(x1, x2, x3, gstart, pooled);
    head_kernel<<<(GRAPHS + 255) / 256, 256, 0, stream>>>(pooled, gstart, Wo, bo, out);
}

// Round 14
// 491.175 us; speedup vs baseline: 1.4543x; 1.0725x over previous
//
#include <hip/hip_runtime.h>
#include <hip/hip_bf16.h>

#define F 64
#define GRAPHS 512
#define CLASSES 10
#define SCAN_T 1024
#define NBLK 256       // histogram/scatter blocks (power of 2)
#define OUTCAP 8448    // bucket CSR slots (mean ~4350, sigma ~64 — never overflows)

// ---------------- phase 1: per-block LDS histogram (+gbounds, +W1 transpose) ----------------
__global__ void hist_gb_kernel(const int* __restrict__ ei, int E, int NB,
                               int* __restrict__ hist,
                               const int* __restrict__ batch, int N, int* __restrict__ gstart,
                               const float* __restrict__ W1, float* __restrict__ Wt) {
    int blk = blockIdx.x, tid = threadIdx.x;
    if (blk < NBLK) {
        __shared__ int lh[512];
        lh[tid] = 0; lh[tid + 256] = 0;
        __syncthreads();
        int chunk = (E + NBLK - 1) / NBLK;
        int b = blk * chunk, e = min(E, b + chunk);
        for (int i = b + tid; i < e; i += 256) atomicAdd(&lh[ei[E + i] >> 8], 1);
        __syncthreads();
        for (int j = tid; j < NB; j += 256) hist[j * NBLK + blk] = lh[j];
    } else if (blk < NBLK + 3) {
        int g = (blk - NBLK) * 256 + tid;
        if (g > GRAPHS) return;
        int lo = 0, hi = N;
        while (lo < hi) {
            int mid = (lo + hi) >> 1;
            if (batch[mid] < g) lo = mid + 1; else hi = mid;
        }
        gstart[g] = lo;
    } else {
        // W1 transpose: Wt[c][k] = W1[k][c]  (64 x 128)
        int c = tid & 63;
        int k0 = (tid >> 6) * 32;
        for (int k = k0; k < k0 + 32; ++k) Wt[c * 128 + k] = W1[k * 64 + c];
    }
}

// ---------------- phase 2: exclusive scan of hist (contiguous layout) ----------------
__global__ void hscan_partial(const int* __restrict__ hist, int M,
                              int* __restrict__ partial) {
    int t = blockIdx.x * blockDim.x + threadIdx.x;
    int chunk = (M + SCAN_T - 1) / SCAN_T;
    int b = t * chunk, e = min(M, b + chunk);
    int s = 0;
    for (int l = b; l < e; ++l) s += hist[l];
    partial[t] = s;
}

__global__ void scan_block(int* __restrict__ partial) {   // 1 block, 1024 threads
    __shared__ int wsum[16];
    int t = threadIdx.x;
    int lane = t & 63, w = t >> 6;
    int orig = partial[t];
    int v = orig;
    #pragma unroll
    for (int o = 1; o < 64; o <<= 1) {
        int u = __shfl_up(v, o);
        if (lane >= o) v += u;
    }
    if (lane == 63) wsum[w] = v;
    __syncthreads();
    if (t == 0) {
        int run = 0;
        for (int i = 0; i < 16; ++i) { int x = wsum[i]; wsum[i] = run; run += x; }
    }
    __syncthreads();
    v += wsum[w];
    partial[t] = v - orig;   // exclusive prefix
}

__global__ void hscan_final(const int* __restrict__ hist, const int* __restrict__ partial,
                            int M, int* __restrict__ shist) {
    int t = blockIdx.x * blockDim.x + threadIdx.x;
    int chunk = (M + SCAN_T - 1) / SCAN_T;
    int b = t * chunk, e = min(M, b + chunk);
    int run = partial[t];
    for (int l = b; l < e; ++l) {
        int v = hist[l];
        shist[l] = run;
        run += v;
    }
}

// ---------------- phase 3: binned scatter, LDS cursors only ----------------
__global__ void scatter3(const int* __restrict__ ei, int E, int NB,
                         const int* __restrict__ shist, unsigned* __restrict__ stage) {
    __shared__ int offs[512];
    int blk = blockIdx.x, tid = threadIdx.x;
    for (int j = tid; j < NB; j += 256) offs[j] = shist[j * NBLK + blk];
    __syncthreads();
    int chunk = (E + NBLK - 1) / NBLK;
    int b = blk * chunk, e = min(E, b + chunk);
    for (int i = b + tid; i < e; i += 256) {
        int s = ei[i], d = ei[E + i];
        int pos = atomicAdd(&offs[d >> 8], 1);
        stage[pos] = (unsigned)s | ((unsigned)(d & 255) << 24);
    }
}

// ---------------- phase 4: per-bucket place; derives rowptr; coalesced CSR flush ---------
__global__ void place2(const unsigned* __restrict__ stage, const int* __restrict__ shist,
                       int* __restrict__ rowptr, int* __restrict__ csr_src,
                       int N, int E, int NB) {
    __shared__ int cnt[256];
    __shared__ int cur[256];
    __shared__ int wsum[4];
    __shared__ int out[OUTCAP];
    int tid = threadIdx.x, bkt = blockIdx.x;
    int n0 = bkt << 8;
    int nn = min(256, N - n0);
    int eb = shist[bkt * NBLK];
    int ee = (bkt == NB - 1) ? E : shist[(bkt + 1) * NBLK];
    int elen = ee - eb;
    int cb = eb + n0;
    int csrlen = elen + nn;
    cnt[tid] = 0;
    __syncthreads();
    for (int i = tid; i < elen; i += 256) atomicAdd(&cnt[stage[eb + i] >> 24], 1);
    __syncthreads();
    int v = (tid < nn) ? cnt[tid] + 1 : 0;
    int lane = tid & 63, w = tid >> 6;
    int incl = v;
    #pragma unroll
    for (int o = 1; o < 64; o <<= 1) {
        int u = __shfl_up(incl, o);
        if (lane >= o) incl += u;
    }
    if (lane == 63) wsum[w] = incl;
    __syncthreads();
    if (tid == 0) {
        int run = 0;
        for (int i = 0; i < 4; ++i) { int t = wsum[i]; wsum[i] = run; run += t; }
    }
    __syncthreads();
    int excl = incl - v + wsum[w];
    cur[tid] = excl;
    if (tid < nn) rowptr[n0 + tid] = cb + excl;
    if (bkt == NB - 1 && tid == 0) rowptr[N] = E + N;
    __syncthreads();
    if (csrlen <= OUTCAP) {
        for (int i = tid; i < elen; i += 256) {
            unsigned wd = stage[eb + i];
            int p = atomicAdd(&cur[wd >> 24], 1);
            out[p] = (int)(wd & 0xFFFFFFu);
        }
        __syncthreads();
        if (tid < nn) out[cur[tid]] = n0 + tid;
        __syncthreads();
        for (int i = tid; i < csrlen; i += 256) csr_src[cb + i] = out[i];
    } else {
        for (int i = tid; i < elen; i += 256) {
            unsigned wd = stage[eb + i];
            int p = atomicAdd(&cur[wd >> 24], 1);
            csr_src[cb + p] = (int)(wd & 0xFFFFFFu);
        }
        __syncthreads();
        if (tid < nn) csr_src[cb + cur[tid]] = n0 + tid;
    }
}

// ---------------- layer-1 GEMM (K=128): W in LDS (staged from pre-transposed Wt) ----------
// R13 lesson: streaming W per-lane from global (lane*512B stride) makes every load touch
// 64 L1 lines — slower than LDS even when fully cache-resident. LDS + KP=132 padding is
// conflict-free (measured 0 SQ_LDS_BANK_CONFLICT at 69us in R9/R11). Do not re-stream.
__global__ void gemm_kernel(const float* __restrict__ x, const float* __restrict__ Wt,
                            const float* __restrict__ asrc, const float* __restrict__ adst,
                            unsigned* __restrict__ hb, float* __restrict__ es,
                            float* __restrict__ ed, int N) {
    constexpr int ROWS = 16;
    constexpr int K = 128;
    constexpr int KP = K + 4;
    constexpr int K4 = K / 4;
    __shared__ float Ws[64 * KP];
    __shared__ float xs[ROWS * K];
    __shared__ unsigned hs[ROWS * 32];
    int base = blockIdx.x * ROWS;

    // stage Ws from pre-transposed Wt: straight coalesced copy (read + write, no gather)
    {
        const float4* Wt4 = (const float4*)Wt;
        for (int i = threadIdx.x; i < 64 * K4; i += 256) {
            int c = i >> 5, q = i & 31;
            *(float4*)&Ws[c * KP + 4 * q] = Wt4[i];
        }
    }
    int nrows = min(ROWS, N - base);
    float4* xs4 = (float4*)xs;
    const float4* x4 = (const float4*)x;
    for (int i = threadIdx.x; i < nrows * K4; i += 256) {
        int r = i / K4, k4 = i - r * K4;
        xs4[r * K4 + k4] = x4[(size_t)(base + r) * K4 + k4];
    }
    __syncthreads();

    int wave = threadIdx.x >> 6, lane = threadIdx.x & 63;
    float as_l = asrc[lane];
    float ad_l = adst[lane];
    const float4* wr = (const float4*)&Ws[lane * KP];
    const float4* xr0 = (const float4*)&xs[(wave + 0) * K];
    const float4* xr1 = (const float4*)&xs[(wave + 4) * K];
    const float4* xr2 = (const float4*)&xs[(wave + 8) * K];
    const float4* xr3 = (const float4*)&xs[(wave + 12) * K];
    float a0 = 0.f, a1 = 0.f, a2 = 0.f, a3 = 0.f;
    #pragma unroll 8
    for (int k4 = 0; k4 < K4; ++k4) {
        float4 wv = wr[k4];
        float4 v0 = xr0[k4], v1 = xr1[k4], v2 = xr2[k4], v3 = xr3[k4];
        a0 = fmaf(v0.x, wv.x, fmaf(v0.y, wv.y, fmaf(v0.z, wv.z, fmaf(v0.w, wv.w, a0))));
        a1 = fmaf(v1.x, wv.x, fmaf(v1.y, wv.y, fmaf(v1.z, wv.z, fmaf(v1.w, wv.w, a1))));
        a2 = fmaf(v2.x, wv.x, fmaf(v2.y, wv.y, fmaf(v2.z, wv.z, fmaf(v2.w, wv.w, a2))));
        a3 = fmaf(v3.x, wv.x, fmaf(v3.y, wv.y, fmaf(v3.z, wv.z, fmaf(v3.w, wv.w, a3))));
    }
    float accs[4] = {a0, a1, a2, a3};
    #pragma unroll
    for (int rr = 0; rr < 4; ++rr) {
        int r = wave + 4 * rr;
        float acc = accs[rr];
        unsigned ub = __float_as_uint(acc);
        unsigned rb = (ub + 0x7FFF + ((ub >> 16) & 1)) >> 16;   // RNE bf16 bits
        unsigned pb = (unsigned)__shfl_xor((int)rb, 1);
        if ((lane & 1) == 0) hs[r * 32 + (lane >> 1)] = (pb << 16) | rb;
        float vs = acc * as_l;
        float vd = acc * ad_l;
        #pragma unroll
        for (int o = 32; o > 0; o >>= 1) {
            vs += __shfl_down(vs, o);
            vd += __shfl_down(vd, o);
        }
        if (lane == 0 && r < nrows) { es[base + r] = vs; ed[base + r] = vd; }
    }
    __syncthreads();
    unsigned* hbase = hb + (size_t)base * 32;
    for (int i = threadIdx.x; i < nrows * 32; i += 256) hbase[i] = hs[i];
}

// ---------------- aggregate: 2 nodes per wave; optional fused next-layer GEMM epilogue ----
// Epilogue kept as two independent per-row loops: the "hoisted" 8-accumulator variant
// raised register demand past the compiler's cap and spilled INSIDE the gather loop
// (R12: VGPR 28->64, +555MB HBM scratch traffic, agg 83->176us). Do not re-hoist.
template<bool FUSE>
__global__ void gat_agg_fused(const unsigned* __restrict__ hb_in, const float* __restrict__ es_in,
                              const float* __restrict__ ed_in, const int* __restrict__ rowptr,
                              const int* __restrict__ csr_src, const float* __restrict__ bias,
                              const float* __restrict__ Wn, const float* __restrict__ ans,
                              const float* __restrict__ and_,
                              float* __restrict__ xout, unsigned* __restrict__ hb_out,
                              float* __restrict__ es_out, float* __restrict__ ed_out, int N) {
    extern __shared__ float smem[];
    constexpr int KP = 68;
    float* Ws = smem;                                        // [64][68] (FUSE only)
    float2* sw = (float2*)(smem + (FUSE ? 64 * KP : 0));     // [8][64] (src,w) pairs
    float* xs = (float*)((char*)sw + 8 * 64 * 8);            // [8][64] output rows
    unsigned* hpack = (unsigned*)((char*)xs + 8 * 64 * 4);   // [8][32] (FUSE only)

    int wave = threadIdx.x >> 6, lane = threadIdx.x & 63;
    int hw = lane >> 5, sub = lane & 31;
    int base8 = blockIdx.x * 8;
    int nl = 2 * wave + hw;                // node-local 0..7
    int node = base8 + nl;

    if (FUSE) {
        int c = threadIdx.x & 63;
        int q0 = threadIdx.x >> 6;
        #pragma unroll
        for (int it = 0; it < 4; ++it) {
            int q = q0 + 4 * it;
            float4 v;
            v.x = Wn[(4 * q + 0) * F + c];
            v.y = Wn[(4 * q + 1) * F + c];
            v.z = Wn[(4 * q + 2) * F + c];
            v.w = Wn[(4 * q + 3) * F + c];
            *(float4*)&Ws[c * KP + 4 * q] = v;
        }
    }

    if (node < N) {
        int beg = rowptr[node], end = rowptr[node + 1];
        int cnt = end - beg;
        float edn = ed_in[node];
        float accL, accH, den;
        if (cnt <= 64) {
            int s1 = 0, s2 = 0;
            float e1 = -1e30f, e2 = -1e30f;
            if (sub < cnt) {
                s1 = csr_src[beg + sub];
                float t = es_in[s1] + edn;
                e1 = t > 0.f ? t : 0.2f * t;
            }
            if (sub + 32 < cnt) {
                s2 = csr_src[beg + 32 + sub];
                float t = es_in[s2] + edn;
                e2 = t > 0.f ? t : 0.2f * t;
            }
            float m = fmaxf(e1, e2);
            #pragma unroll
            for (int o = 16; o > 0; o >>= 1) m = fmaxf(m, __shfl_xor(m, o));
            float w1 = (sub < cnt) ? __expf(e1 - m) : 0.f;
            float w2 = (sub + 32 < cnt) ? __expf(e2 - m) : 0.f;
            den = w1 + w2;
            #pragma unroll
            for (int o = 16; o > 0; o >>= 1) den += __shfl_xor(den, o);
            sw[nl * 64 + sub] = make_float2(__int_as_float(s1), w1);
            sw[nl * 64 + 32 + sub] = make_float2(__int_as_float(s2), w2);
            float l0 = 0.f, l1 = 0.f, l2 = 0.f, l3 = 0.f;
            float h0 = 0.f, h1 = 0.f, h2 = 0.f, h3 = 0.f;
            int i = 0;
            for (; i + 3 < cnt; i += 4) {
                float2 p0 = sw[nl * 64 + i];
                float2 p1 = sw[nl * 64 + i + 1];
                float2 p2 = sw[nl * 64 + i + 2];
                float2 p3 = sw[nl * 64 + i + 3];
                unsigned q0 = hb_in[(size_t)__float_as_int(p0.x) * 32 + sub];
                unsigned q1 = hb_in[(size_t)__float_as_int(p1.x) * 32 + sub];
                unsigned q2 = hb_in[(size_t)__float_as_int(p2.x) * 32 + sub];
                unsigned q3 = hb_in[(size_t)__float_as_int(p3.x) * 32 + sub];
                l0 = fmaf(p0.y, __uint_as_float(q0 << 16), l0);
                h0 = fmaf(p0.y, __uint_as_float(q0 & 0xFFFF0000u), h0);
                l1 = fmaf(p1.y, __uint_as_float(q1 << 16), l1);
                h1 = fmaf(p1.y, __uint_as_float(q1 & 0xFFFF0000u), h1);
                l2 = fmaf(p2.y, __uint_as_float(q2 << 16), l2);
                h2 = fmaf(p2.y, __uint_as_float(q2 & 0xFFFF0000u), h2);
                l3 = fmaf(p3.y, __uint_as_float(q3 << 16), l3);
                h3 = fmaf(p3.y, __uint_as_float(q3 & 0xFFFF0000u), h3);
            }
            for (; i < cnt; ++i) {
                float2 pp = sw[nl * 64 + i];
                unsigned q = hb_in[(size_t)__float_as_int(pp.x) * 32 + sub];
                l0 = fmaf(pp.y, __uint_as_float(q << 16), l0);
                h0 = fmaf(pp.y, __uint_as_float(q & 0xFFFF0000u), h0);
            }
            accL = (l0 + l1) + (l2 + l3);
            accH = (h0 + h1) + (h2 + h3);
        } else {
            float m = -1e30f;
            for (int j = beg + sub; j < end; j += 32) {
                float e = es_in[csr_src[j]] + edn;
                e = e > 0.f ? e : 0.2f * e;
                m = fmaxf(m, e);
            }
            #pragma unroll
            for (int o = 16; o > 0; o >>= 1) m = fmaxf(m, __shfl_xor(m, o));
            accL = 0.f; accH = 0.f; den = 0.f;
            for (int j = beg; j < end; ++j) {
                int s = csr_src[j];
                float e = es_in[s] + edn;
                e = e > 0.f ? e : 0.2f * e;
                float w = __expf(e - m);
                den += w;
                unsigned q = hb_in[(size_t)s * 32 + sub];
                accL = fmaf(w, __uint_as_float(q << 16), accL);
                accH = fmaf(w, __uint_as_float(q & 0xFFFF0000u), accH);
            }
        }
        float inv = 1.0f / (den + 1e-16f);
        float2 b2v = ((const float2*)bias)[sub];
        float vL = accL * inv + b2v.x;
        float vH = accH * inv + b2v.y;
        vL = vL > 0.f ? vL : 0.f;
        vH = vH > 0.f ? vH : 0.f;
        ((float2*)&xs[nl * 64])[sub] = make_float2(vL, vH);
    }
    __syncthreads();

    int nrows = min(8, N - base8);
    {
        float* xbase = xout + (size_t)base8 * F;
        for (int i = threadIdx.x; i < nrows * 64; i += 256) xbase[i] = xs[i];
    }

    if (FUSE) {
        float as_l = ans[lane];
        float ad_l = and_[lane];
        #pragma unroll
        for (int rr = 0; rr < 2; ++rr) {
            int r = wave + 4 * rr;
            int nd = base8 + r;
            if (nd < N) {
                const float4* xv4 = (const float4*)&xs[r * 64];
                const float4* wv4 = (const float4*)&Ws[lane * KP];
                float a0 = 0.f, a1 = 0.f, a2 = 0.f, a3 = 0.f;
                #pragma unroll
                for (int k4 = 0; k4 < 16; ++k4) {
                    float4 xv = xv4[k4];
                    float4 wv = wv4[k4];
                    a0 = fmaf(xv.x, wv.x, a0);
                    a1 = fmaf(xv.y, wv.y, a1);
                    a2 = fmaf(xv.z, wv.z, a2);
                    a3 = fmaf(xv.w, wv.w, a3);
                }
                float hacc = (a0 + a1) + (a2 + a3);
                float vs = hacc * as_l;
                float vd = hacc * ad_l;
                #pragma unroll
                for (int o = 32; o > 0; o >>= 1) {
                    vs += __shfl_down(vs, o);
                    vd += __shfl_down(vd, o);
                }
                if (lane == 0) { es_out[nd] = vs; ed_out[nd] = vd; }
                unsigned ub = __float_as_uint(hacc);
                unsigned rb = (ub + 0x7FFF + ((ub >> 16) & 1)) >> 16;
                unsigned pb = (unsigned)__shfl_xor((int)rb, 1);
                if ((lane & 1) == 0) hpack[r * 32 + (lane >> 1)] = (pb << 16) | rb;
            }
        }
        __syncthreads();
        unsigned* hbase = hb_out + (size_t)base8 * 32;
        for (int i = threadIdx.x; i < nrows * 32; i += 256) hbase[i] = hpack[i];
    }
}

// ---------------- mean pooling ----------------
__global__ void pool_kernel(const float* __restrict__ x1, const float* __restrict__ x2,
                            const float* __restrict__ x3, const int* __restrict__ gstart,
                            float* __restrict__ pooled) {
    int g = blockIdx.x >> 2;
    int seg = blockIdx.x & 3;
    int f = threadIdx.x;
    int lane = f & 63;
    const float* src = (f < 64) ? x1 : (f < 128) ? x2 : x3;
    int lo = gstart[g], hi = gstart[g + 1];
    int len = hi - lo;
    int chunk = (len + 3) >> 2;
    int b = lo + seg * chunk;
    int e = min(hi, b + chunk);
    float s0 = 0.f, s1 = 0.f, s2 = 0.f, s3 = 0.f;
    int i = b;
    for (; i + 3 < e; i += 4) {
        s0 += src[(size_t)i * F + lane];
        s1 += src[(size_t)(i + 1) * F + lane];
        s2 += src[(size_t)(i + 2) * F + lane];
        s3 += src[(size_t)(i + 3) * F + lane];
    }
    for (; i < e; ++i) s0 += src[(size_t)i * F + lane];
    float s = (s0 + s1) + (s2 + s3);
    atomicAdd(&pooled[g * 192 + f], s);
}

// ---------------- final linear + softmax ----------------
__global__ void head_kernel(const float* __restrict__ pooled, const int* __restrict__ gstart,
                            const float* __restrict__ Wo, const float* __restrict__ bo,
                            float* __restrict__ out) {
    int g = blockIdx.x * blockDim.x + threadIdx.x;
    if (g >= GRAPHS) return;
    int cntg = gstart[g + 1] - gstart[g];
    float inv = 1.0f / fmaxf((float)cntg, 1.0f);
    float acc[CLASSES];
    #pragma unroll
    for (int c = 0; c < CLASSES; ++c) acc[c] = bo[c];
    for (int f = 0; f < 192; ++f) {
        float p = pooled[g * 192 + f] * inv;
        #pragma unroll
        for (int c = 0; c < CLASSES; ++c) acc[c] = fmaf(p, Wo[f * CLASSES + c], acc[c]);
    }
    float mx = acc[0];
    #pragma unroll
    for (int c = 1; c < CLASSES; ++c) mx = fmaxf(mx, acc[c]);
    float s = 0.f;
    #pragma unroll
    for (int c = 0; c < CLASSES; ++c) { acc[c] = __expf(acc[c] - mx); s += acc[c]; }
    float invs = 1.0f / s;
    #pragma unroll
    for (int c = 0; c < CLASSES; ++c) out[g * CLASSES + c] = acc[c] * invs;
}

extern "C" void kernel_launch(void* const* d_in, const int* in_sizes, int n_in,
                              void* d_out, int out_size, void* d_ws, size_t ws_size,
                              hipStream_t stream) {
    const float* x   = (const float*)d_in[0];
    const int* ei    = (const int*)d_in[1];
    const int* batch = (const int*)d_in[2];
    const float* W1  = (const float*)d_in[3];
    const float* a1s = (const float*)d_in[4];
    const float* a1d = (const float*)d_in[5];
    const float* b1  = (const float*)d_in[6];
    const float* W2  = (const float*)d_in[7];
    const float* a2s = (const float*)d_in[8];
    const float* a2d = (const float*)d_in[9];
    const float* b2  = (const float*)d_in[10];
    const float* W3  = (const float*)d_in[11];
    const float* a3s = (const float*)d_in[12];
    const float* a3d = (const float*)d_in[13];
    const float* b3  = (const float*)d_in[14];
    const float* Wo  = (const float*)d_in[15];
    const float* bo  = (const float*)d_in[16];
    float* out = (float*)d_out;

    const int N = in_sizes[2];
    const int E = in_sizes[1] / 2;
    const int TOT = E + N;
    const int NB = (N + 255) >> 8;
    const int M  = NB * NBLK;

    char* p = (char*)d_ws;
    auto alloc = [&](size_t bytes) { char* r = p; p += (bytes + 255) & ~(size_t)255; return r; };
    float* x1      = (float*)alloc((size_t)N * F * 4);
    float* x2      = (float*)alloc((size_t)N * F * 4);
    float* x3      = (float*)alloc((size_t)N * F * 4);
    unsigned* hbA  = (unsigned*)alloc((size_t)N * 32 * 4);
    unsigned* hbB  = (unsigned*)alloc((size_t)N * 32 * 4);
    float* esA     = (float*)alloc((size_t)N * 4);
    float* edA     = (float*)alloc((size_t)N * 4);
    float* esB     = (float*)alloc((size_t)N * 4);
    float* edB     = (float*)alloc((size_t)N * 4);
    int* rowptr    = (int*)alloc((size_t)(N + 1) * 4);
    int* csr_src   = (int*)alloc((size_t)TOT * 4);
    unsigned* stage= (unsigned*)alloc((size_t)E * 4);
    int* hist      = (int*)alloc((size_t)M * 4);
    int* shist     = (int*)alloc((size_t)M * 4);
    int* partial   = (int*)alloc((size_t)SCAN_T * 4);
    float* pooled  = (float*)alloc((size_t)GRAPHS * 192 * 4);
    int* gstart    = (int*)alloc((size_t)(GRAPHS + 1) * 4);
    float* Wt      = (float*)alloc((size_t)128 * 64 * 4);    // W1 transposed

    hipMemsetAsync(pooled, 0, (size_t)GRAPHS * 192 * 4, stream);

    const int GB = (N + 15) / 16;
    const size_t SMF   = (size_t)(64 * 68) * 4 + 4096 + 2048 + 1024;   // Ws + sw + xs + hpack
    const size_t SMNF  = 4096 + 2048 + 1024;
    int agg_blocks = (N + 7) / 8;

    // CSR build (+ gbounds + W1 transpose riding along)
    hist_gb_kernel<<<NBLK + 4, 256, 0, stream>>>(ei, E, NB, hist, batch, N, gstart, W1, Wt);
    hscan_partial<<<SCAN_T / 256, 256, 0, stream>>>(hist, M, partial);
    scan_block<<<1, SCAN_T, 0, stream>>>(partial);
    hscan_final<<<SCAN_T / 256, 256, 0, stream>>>(hist, partial, M, shist);
    scatter3<<<NBLK, 256, 0, stream>>>(ei, E, NB, shist, stage);
    place2<<<NB, 256, 0, stream>>>(stage, shist, rowptr, csr_src, N, E, NB);

    // layer 1 GEMM (K=128), W staged to LDS from pre-transposed Wt
    gemm_kernel<<<GB, 256, 0, stream>>>(x, Wt, a1s, a1d, hbA, esA, edA, N);
    // agg1 + fused gemm2
    gat_agg_fused<true><<<agg_blocks, 256, SMF, stream>>>(hbA, esA, edA, rowptr, csr_src, b1,
                                                          W2, a2s, a2d, x1, hbB, esB, edB, N);
    // agg2 + fused gemm3
    gat_agg_fused<true><<<agg_blocks, 256, SMF, stream>>>(hbB, esB, edB, rowptr, csr_src, b2,
                                                          W3, a3s, a3d, x2, hbA, esA, edA, N);
    // agg3 (no fusion)
    gat_agg_fused<false><<<agg_blocks, 256, SMNF, stream>>>(hbA, esA, edA, rowptr, csr_src, b3,
                                                            nullptr, nullptr, nullptr,
                                                            x3, nullptr, nullptr, nullptr, N);

    // readout
    pool_kernel<<<GRAPHS * 4, 192, 0, stream>>>(x1, x2, x3, gstart, pooled);
    head_kernel<<<(GRAPHS + 255) / 256, 256, 0, stream>>>(pooled, gstart, Wo, bo, out);
}